// Round 8
// baseline (96.587 us; speedup 1.0000x reference)
//
#include <hip/hip_runtime.h>
#include <hip/hip_cooperative_groups.h>
#include <math.h>

namespace cg = cooperative_groups;

#define N  512
#define C  256          // distinct label-diff classes per row (labels repeat)
#define D  128
#define NT 16           // 32-col tiles per row

// Single cooperative kernel: P0 (logit tiles + partials) -> grid.sync -> P1 (per-row loss)
__global__ __launch_bounds__(256) void mega(const float* __restrict__ feat,
                                            const float* __restrict__ labels,
                                            float* __restrict__ lg,
                                            float* __restrict__ rmax_p,
                                            float* __restrict__ rsum_p,
                                            float* __restrict__ acc,
                                            unsigned* __restrict__ cnt,
                                            float* __restrict__ out) {
    const int b = blockIdx.x;
    const int tid = threadIdx.x;

    __shared__ union {
        struct { float4 As[32][32]; float4 Bs[32][32]; } p0;          // 32 KB
        struct { float sld[C]; float sev[C]; float red[4]; float lci; } p1;
    } sm;

    // reset accumulators every call via fabric-level atomic stores (graph-replay safe;
    // ordered before P1's adds by the grid.sync between them)
    if (b == 0 && tid == 0) {
        __hip_atomic_store(acc, 0.f, __ATOMIC_RELAXED, __HIP_MEMORY_SCOPE_AGENT);
        __hip_atomic_store(cnt, 0u, __ATOMIC_RELAXED, __HIP_MEMORY_SCOPE_AGENT);
    }

    // ---------------- P0: 32x32 logit tile (R4-proven body) + partials ----------------
    if (b < 256) {
        const int row0 = (b >> 4) << 5;
        const int col0 = (b & 15) << 5;

        const float4* f4 = (const float4*)feat;   // [512][32]
        {
            const int r = tid >> 5, c4 = tid & 31;
#pragma unroll
            for (int p = 0; p < 4; ++p) {
                const int rr = r + p * 8;
                const int sc = c4 ^ ((rr >> 1) & 7);
                sm.p0.As[rr][sc] = f4[(size_t)(row0 + rr) * 32 + c4];
                sm.p0.Bs[rr][sc] = f4[(size_t)(col0 + rr) * 32 + c4];
            }
        }
        __syncthreads();

        const int ty = tid >> 4, tx = tid & 15;
        const int r0 = 2 * ty, r1 = 2 * ty + 1;
        const int c0 = 2 * tx, c1 = 2 * tx + 1;
        const int sa = ty & 7, sb = tx & 7;

        float s00 = 0.f, s01 = 0.f, s10 = 0.f, s11 = 0.f;
#pragma unroll 8
        for (int q = 0; q < 32; ++q) {
            float4 a0 = sm.p0.As[r0][q ^ sa];
            float4 a1 = sm.p0.As[r1][q ^ sa];
            float4 b0 = sm.p0.Bs[c0][q ^ sb];
            float4 b1 = sm.p0.Bs[c1][q ^ sb];
            float t;
            t = a0.x - b0.x; s00 = fmaf(t, t, s00);
            t = a0.y - b0.y; s00 = fmaf(t, t, s00);
            t = a0.z - b0.z; s00 = fmaf(t, t, s00);
            t = a0.w - b0.w; s00 = fmaf(t, t, s00);
            t = a0.x - b1.x; s01 = fmaf(t, t, s01);
            t = a0.y - b1.y; s01 = fmaf(t, t, s01);
            t = a0.z - b1.z; s01 = fmaf(t, t, s01);
            t = a0.w - b1.w; s01 = fmaf(t, t, s01);
            t = a1.x - b0.x; s10 = fmaf(t, t, s10);
            t = a1.y - b0.y; s10 = fmaf(t, t, s10);
            t = a1.z - b0.z; s10 = fmaf(t, t, s10);
            t = a1.w - b0.w; s10 = fmaf(t, t, s10);
            t = a1.x - b1.x; s11 = fmaf(t, t, s11);
            t = a1.y - b1.y; s11 = fmaf(t, t, s11);
            t = a1.z - b1.z; s11 = fmaf(t, t, s11);
            t = a1.w - b1.w; s11 = fmaf(t, t, s11);
        }
        // safe_l2: identical rows give s == 0 exactly -> logit 0 (diagonal)
        float l00 = (s00 > 0.f) ? -0.5f * sqrtf(s00) : 0.f;
        float l01 = (s01 > 0.f) ? -0.5f * sqrtf(s01) : 0.f;
        float l10 = (s10 > 0.f) ? -0.5f * sqrtf(s10) : 0.f;
        float l11 = (s11 > 0.f) ? -0.5f * sqrtf(s11) : 0.f;

        const int gr0 = row0 + r0, gr1 = row0 + r1;
        const int gc0 = col0 + c0, gc1 = col0 + c1;

        *(float2*)(lg + (size_t)gr0 * N + gc0) = make_float2(l00, l01);
        *(float2*)(lg + (size_t)gr1 * N + gc0) = make_float2(l10, l11);

        // per-tile partial row-max (excluding diagonal) and row-sum (diag lg == 0, include)
        float m0 = fmaxf((gr0 == gc0) ? -1e30f : l00, (gr0 == gc1) ? -1e30f : l01);
        float m1 = fmaxf((gr1 == gc0) ? -1e30f : l10, (gr1 == gc1) ? -1e30f : l11);
        float u0 = l00 + l01;
        float u1 = l10 + l11;
#pragma unroll
        for (int off = 1; off < 16; off <<= 1) {      // reduce across the 16 tx lanes
            m0 = fmaxf(m0, __shfl_xor(m0, off, 64));
            m1 = fmaxf(m1, __shfl_xor(m1, off, 64));
            u0 += __shfl_xor(u0, off, 64);
            u1 += __shfl_xor(u1, off, 64);
        }
        const int jt = b & 15;
        if (tx == 0) {
            rmax_p[(size_t)gr0 * NT + jt] = m0;
            rmax_p[(size_t)gr1 * NT + jt] = m1;
            rsum_p[(size_t)gr0 * NT + jt] = u0;
            rsum_p[(size_t)gr1 * NT + jt] = u1;
        }
    }

    cg::this_grid().sync();

    // ---------------- P1: block i = row i, thread c = class c ----------------
    {
        const int i = b;
        const int c = tid;

        // m and rowsum from the 16 partials (lane-spread loads -> vector path)
        float mp = rmax_p[(size_t)i * NT + (tid & 15)];
        float sp = rsum_p[(size_t)i * NT + (tid & 15)];
#pragma unroll
        for (int off = 1; off < 16; off <<= 1) {
            mp = fmaxf(mp, __shfl_xor(mp, off, 64));
            sp += __shfl_xor(sp, off, 64);
        }
        const float m = mp;
        const float rowsum = sp - 511.f * m;   // sum_{k!=i}(lg_k - m), lg_i == 0

        // exp values; diagonal forced to 0 drops it from every denominator
        const float la = lg[(size_t)i * N + c];
        const float lb = lg[(size_t)i * N + c + 256];
        const float ea = (c == i) ? 0.f : __expf(la - m);
        const float eb = (c + 256 == i) ? 0.f : __expf(lb - m);
        sm.p1.sev[c] = ea + eb;

        // label diff per class (bitwise identical to reference f32 math)
        const float2 lc2 = ((const float2*)labels)[c];
        const float2 li2 = ((const float2*)labels)[i & 255];
        const float ldk = fabsf(li2.x - lc2.x) + fabsf(li2.y - lc2.y);
        sm.p1.sld[c] = ldk;
        __syncthreads();

        // denominator scan (wave-uniform LDS float4 broadcasts)
        const float4* a4 = (const float4*)sm.p1.sld;
        const float4* b4 = (const float4*)sm.p1.sev;
        float d0 = 0.f, d1 = 0.f, d2 = 0.f, d3 = 0.f;
#pragma unroll 8
        for (int q = 0; q < C / 4; ++q) {
            float4 a = a4[q];
            float4 bb = b4[q];
            d0 += (a.x >= ldk) ? bb.x : 0.f;
            d1 += (a.y >= ldk) ? bb.y : 0.f;
            d2 += (a.z >= ldk) ? bb.z : 0.f;
            d3 += (a.w >= ldk) ? bb.w : 0.f;
        }
        const float lden = __logf((d0 + d1) + (d2 + d3));

        if (c == (i & 255)) sm.p1.lci = lden;   // class(i): ld == 0 -> den == total ev sum
        float s = lden;
#pragma unroll
        for (int off = 32; off > 0; off >>= 1) s += __shfl_xor(s, off, 64);
        if ((c & 63) == 0) sm.p1.red[c >> 6] = s;
        __syncthreads();

        if (c == 0) {
            const float tot  = sm.p1.red[0] + sm.p1.red[1] + sm.p1.red[2] + sm.p1.red[3];
            const float part = rowsum - (2.f * tot - sm.p1.lci);

            // fence-free last-arriver: acc-RMW acked (forced use of return) BEFORE cnt-RMW,
            // so cnt==N-1 implies all acc adds are complete at the coherence point.
            float r = __hip_atomic_fetch_add(acc, part, __ATOMIC_RELAXED, __HIP_MEMORY_SCOPE_AGENT);
            __asm__ volatile("" :: "v"(r));
            const unsigned prev = __hip_atomic_fetch_add(cnt, 1u, __ATOMIC_RELAXED,
                                                         __HIP_MEMORY_SCOPE_AGENT);
            if (prev == (unsigned)(N - 1)) {
                const float total = __hip_atomic_load(acc, __ATOMIC_RELAXED,
                                                      __HIP_MEMORY_SCOPE_AGENT);
                out[0] = -total / ((float)N * (float)(N - 1));
            }
        }
    }
}

extern "C" void kernel_launch(void* const* d_in, const int* in_sizes, int n_in,
                              void* d_out, int out_size, void* d_ws, size_t ws_size,
                              hipStream_t stream) {
    const float* feat   = (const float*)d_in[0];   // [512,128] f32
    const float* labels = (const float*)d_in[1];   // [256,2]  f32
    float* out = (float*)d_out;

    float*    lg     = (float*)d_ws;                       // N*N
    float*    rmax_p = lg + (size_t)N * N;                 // N*NT
    float*    rsum_p = rmax_p + (size_t)N * NT;            // N*NT
    float*    acc    = rsum_p + (size_t)N * NT;            // 1
    unsigned* cnt    = (unsigned*)(acc + 1);               // 1

    void* args[] = { (void*)&feat, (void*)&labels, (void*)&lg, (void*)&rmax_p,
                     (void*)&rsum_p, (void*)&acc, (void*)&cnt, (void*)&out };
    hipLaunchCooperativeKernel((const void*)mega, dim3(512), dim3(256), args, 0, stream);
}

// Round 9
// 30.000 us; speedup vs baseline: 3.2196x; 3.2196x over previous
//
#include <hip/hip_runtime.h>
#include <math.h>

#define N 512
#define C 256          // distinct label-diff classes per row (labels repeat)
#define D 128

// ---------------- K1: all-pairs logits via LDS-staged 32x32 tiles (+ acc/cnt reset) ----------------
__global__ __launch_bounds__(256) void k1_logits(const float* __restrict__ feat,
                                                 float* __restrict__ lg,
                                                 float* __restrict__ acc,
                                                 unsigned* __restrict__ cnt) {
    const int tid = threadIdx.x;
    if (blockIdx.x == 0 && tid == 0) { *acc = 0.f; *cnt = 0u; }   // 2 nodes upstream of use: graph-safe

    const int row0 = (blockIdx.x >> 4) << 5;
    const int col0 = (blockIdx.x & 15) << 5;

    __shared__ float4 As[32][32];   // [row][swizzled q]
    __shared__ float4 Bs[32][32];

    const float4* f4 = (const float4*)feat;   // [512][32]
    {
        const int r = tid >> 5, c4 = tid & 31;
#pragma unroll
        for (int p = 0; p < 4; ++p) {
            const int rr = r + p * 8;
            const int sc = c4 ^ ((rr >> 1) & 7);
            As[rr][sc] = f4[(size_t)(row0 + rr) * 32 + c4];
            Bs[rr][sc] = f4[(size_t)(col0 + rr) * 32 + c4];
        }
    }
    __syncthreads();

    const int ty = tid >> 4, tx = tid & 15;
    const int r0 = 2 * ty, r1 = 2 * ty + 1;
    const int c0 = 2 * tx, c1 = 2 * tx + 1;
    const int sa = ty & 7, sb = tx & 7;

    float s00 = 0.f, s01 = 0.f, s10 = 0.f, s11 = 0.f;
#pragma unroll 8
    for (int q = 0; q < 32; ++q) {
        float4 a0 = As[r0][q ^ sa];
        float4 a1 = As[r1][q ^ sa];
        float4 b0 = Bs[c0][q ^ sb];
        float4 b1 = Bs[c1][q ^ sb];
        float t;
        t = a0.x - b0.x; s00 = fmaf(t, t, s00);
        t = a0.y - b0.y; s00 = fmaf(t, t, s00);
        t = a0.z - b0.z; s00 = fmaf(t, t, s00);
        t = a0.w - b0.w; s00 = fmaf(t, t, s00);
        t = a0.x - b1.x; s01 = fmaf(t, t, s01);
        t = a0.y - b1.y; s01 = fmaf(t, t, s01);
        t = a0.z - b1.z; s01 = fmaf(t, t, s01);
        t = a0.w - b1.w; s01 = fmaf(t, t, s01);
        t = a1.x - b0.x; s10 = fmaf(t, t, s10);
        t = a1.y - b0.y; s10 = fmaf(t, t, s10);
        t = a1.z - b0.z; s10 = fmaf(t, t, s10);
        t = a1.w - b0.w; s10 = fmaf(t, t, s10);
        t = a1.x - b1.x; s11 = fmaf(t, t, s11);
        t = a1.y - b1.y; s11 = fmaf(t, t, s11);
        t = a1.z - b1.z; s11 = fmaf(t, t, s11);
        t = a1.w - b1.w; s11 = fmaf(t, t, s11);
    }
    // safe_l2: identical rows give s == 0 exactly -> logit 0 (diagonal)
    float l00 = (s00 > 0.f) ? -0.5f * sqrtf(s00) : 0.f;
    float l01 = (s01 > 0.f) ? -0.5f * sqrtf(s01) : 0.f;
    float l10 = (s10 > 0.f) ? -0.5f * sqrtf(s10) : 0.f;
    float l11 = (s11 > 0.f) ? -0.5f * sqrtf(s11) : 0.f;

    *(float2*)(lg + (size_t)(row0 + r0) * N + col0 + c0) = make_float2(l00, l01);
    *(float2*)(lg + (size_t)(row0 + r1) * N + col0 + c0) = make_float2(l10, l11);
}

// ---------------- K2: per-row max, exp, class-combine ----------------
__global__ __launch_bounds__(256) void k2_row(const float* __restrict__ lg,
                                              const float* __restrict__ labels,
                                              float* __restrict__ ld2,
                                              float* __restrict__ evs,
                                              float* __restrict__ rowsum) {
    const int i = blockIdx.x;
    const int c = threadIdx.x;

    const float la = lg[(size_t)i * N + c];
    const float lb = lg[(size_t)i * N + c + 256];

    // row max over j != i (lg[i][i] == 0 excluded)
    float m = -1e30f;
    if (c != i) m = la;
    if (c + 256 != i) m = fmaxf(m, lb);
    __shared__ float redm[4];
#pragma unroll
    for (int off = 32; off > 0; off >>= 1) m = fmaxf(m, __shfl_xor(m, off, 64));
    if ((c & 63) == 0) redm[c >> 6] = m;
    __syncthreads();
    m = fmaxf(fmaxf(redm[0], redm[1]), fmaxf(redm[2], redm[3]));

    // exp values; diagonal forced to 0 drops it from every denominator
    float ea = (c == i) ? 0.f : __expf(la - m);
    float eb = (c + 256 == i) ? 0.f : __expf(lb - m);
    evs[(size_t)i * C + c] = ea + eb;

    // label diff per class (bitwise identical to reference f32 math)
    const float2 lc2 = ((const float2*)labels)[c];
    const float2 li2 = ((const float2*)labels)[i & 255];
    ld2[(size_t)i * C + c] = fabsf(li2.x - lc2.x) + fabsf(li2.y - lc2.y);

    // rowsum = sum_{k != i}(lg_k - m) = (sum_k lg_k) - 511*m   (lg_i == 0)
    float s = la + lb;
    __shared__ float reds[4];
#pragma unroll
    for (int off = 32; off > 0; off >>= 1) s += __shfl_xor(s, off, 64);
    if ((c & 63) == 0) reds[c >> 6] = s;
    __syncthreads();
    if (c == 0) rowsum[i] = (reds[0] + reds[1] + reds[2] + reds[3]) - 511.f * m;
}

// ---------------- K3: class denominators + row loss + fence-free last-arriver final ----------------
// Inner loop: wave-uniform scalar global reads of arrays written by a DIFFERENT
// kernel -> s_load path (proven R4). Tail: R8-proven relaxed-atomic last-arriver,
// acc/cnt in d_ws on one cache line, NO fences (R6 showed fences cost ~7-10 us).
__global__ __launch_bounds__(256) void k3_den(const float* __restrict__ ld2,
                                              const float* __restrict__ evs,
                                              const float* __restrict__ rowsum,
                                              float* __restrict__ acc,
                                              unsigned* __restrict__ cnt,
                                              float* __restrict__ out) {
    const int i = blockIdx.x;
    const int c = threadIdx.x;
    const float* __restrict__ rl = ld2 + (size_t)i * C;
    const float* __restrict__ re = evs + (size_t)i * C;
    const float ldk = rl[c];

    float d0 = 0.f, d1 = 0.f, d2 = 0.f, d3 = 0.f;
#pragma unroll 8
    for (int q = 0; q < C; q += 4) {
        float a0 = rl[q + 0], a1 = rl[q + 1], a2 = rl[q + 2], a3 = rl[q + 3];
        float b0 = re[q + 0], b1 = re[q + 1], b2 = re[q + 2], b3 = re[q + 3];
        d0 += (a0 >= ldk) ? b0 : 0.f;
        d1 += (a1 >= ldk) ? b1 : 0.f;
        d2 += (a2 >= ldk) ? b2 : 0.f;
        d3 += (a3 >= ldk) ? b3 : 0.f;
    }
    const float lden = __logf((d0 + d1) + (d2 + d3));

    __shared__ float red[4];
    __shared__ float lci;
    if (c == (i & 255)) lci = lden;   // class(i): ld == 0 -> den == total ev sum
    float s = lden;
#pragma unroll
    for (int off = 32; off > 0; off >>= 1) s += __shfl_xor(s, off, 64);
    if ((c & 63) == 0) red[c >> 6] = s;
    __syncthreads();
    if (c == 0) {
        const float tot  = red[0] + red[1] + red[2] + red[3];
        const float part = rowsum[i] - (2.f * tot - lci);

        // acc-RMW is acked (forced use of returned value) BEFORE the cnt-RMW issues,
        // so observing cnt == N-1 implies all N acc-adds are complete at the L2
        // coherence point (acc and cnt share a cache line). Proven correct in R8.
        float r = __hip_atomic_fetch_add(acc, part, __ATOMIC_RELAXED, __HIP_MEMORY_SCOPE_AGENT);
        __asm__ volatile("" :: "v"(r));
        const unsigned prev = __hip_atomic_fetch_add(cnt, 1u, __ATOMIC_RELAXED,
                                                     __HIP_MEMORY_SCOPE_AGENT);
        if (prev == (unsigned)(N - 1)) {
            const float total = __hip_atomic_load(acc, __ATOMIC_RELAXED,
                                                  __HIP_MEMORY_SCOPE_AGENT);
            out[0] = -total / ((float)N * (float)(N - 1));
        }
    }
}

extern "C" void kernel_launch(void* const* d_in, const int* in_sizes, int n_in,
                              void* d_out, int out_size, void* d_ws, size_t ws_size,
                              hipStream_t stream) {
    const float* feat   = (const float*)d_in[0];   // [512,128] f32
    const float* labels = (const float*)d_in[1];   // [256,2]  f32
    float* out = (float*)d_out;

    float*    lg     = (float*)d_ws;               // N*N
    float*    ld2    = lg + (size_t)N * N;         // N*C
    float*    evs    = ld2 + (size_t)N * C;        // N*C
    float*    rowsum = evs + (size_t)N * C;        // N
    float*    acc    = rowsum + N;                 // 1   (same 64B line as cnt)
    unsigned* cnt    = (unsigned*)(acc + 1);       // 1

    k1_logits<<<256, 256, 0, stream>>>(feat, lg, acc, cnt);
    k2_row  <<<N,   256, 0, stream>>>(lg, labels, ld2, evs, rowsum);
    k3_den  <<<N,   256, 0, stream>>>(ld2, evs, rowsum, acc, cnt, out);
}

// Round 10
// 18.415 us; speedup vs baseline: 5.2449x; 1.6291x over previous
//
#include <hip/hip_runtime.h>
#include <math.h>

#define N 512
#define C 256          // distinct label-diff classes per row (labels repeat)
#define D 128

// ---------------- K1: all-pairs logits via LDS-staged 32x32 tiles + ld2 rows ----------------
// ld2 depends only on labels, so it's produced here; K23 then reads it via the
// cross-kernel scalar-load path (R4-proven fast).
__global__ __launch_bounds__(256) void k1_logits(const float* __restrict__ feat,
                                                 const float* __restrict__ labels,
                                                 float* __restrict__ lg,
                                                 float* __restrict__ ld2) {
    const int tid = threadIdx.x;

    // ld2 rows 2b and 2b+1 (512 elems, 2 per thread) — bitwise same expression as before
    {
        const int i0 = blockIdx.x << 1;
#pragma unroll
        for (int e = tid; e < 2 * C; e += 256) {
            const int row = i0 + (e >> 8);
            const int cc  = e & 255;
            const float2 lc2 = ((const float2*)labels)[cc];
            const float2 li2 = ((const float2*)labels)[row & 255];
            ld2[(size_t)row * C + cc] = fabsf(li2.x - lc2.x) + fabsf(li2.y - lc2.y);
        }
    }

    const int row0 = (blockIdx.x >> 4) << 5;
    const int col0 = (blockIdx.x & 15) << 5;

    __shared__ float4 As[32][32];   // [row][swizzled q]
    __shared__ float4 Bs[32][32];

    const float4* f4 = (const float4*)feat;   // [512][32]
    {
        const int r = tid >> 5, c4 = tid & 31;
#pragma unroll
        for (int p = 0; p < 4; ++p) {
            const int rr = r + p * 8;
            const int sc = c4 ^ ((rr >> 1) & 7);
            As[rr][sc] = f4[(size_t)(row0 + rr) * 32 + c4];
            Bs[rr][sc] = f4[(size_t)(col0 + rr) * 32 + c4];
        }
    }
    __syncthreads();

    const int ty = tid >> 4, tx = tid & 15;
    const int r0 = 2 * ty, r1 = 2 * ty + 1;
    const int c0 = 2 * tx, c1 = 2 * tx + 1;
    const int sa = ty & 7, sb = tx & 7;

    float s00 = 0.f, s01 = 0.f, s10 = 0.f, s11 = 0.f;
#pragma unroll 8
    for (int q = 0; q < 32; ++q) {
        float4 a0 = As[r0][q ^ sa];
        float4 a1 = As[r1][q ^ sa];
        float4 b0 = Bs[c0][q ^ sb];
        float4 b1 = Bs[c1][q ^ sb];
        float t;
        t = a0.x - b0.x; s00 = fmaf(t, t, s00);
        t = a0.y - b0.y; s00 = fmaf(t, t, s00);
        t = a0.z - b0.z; s00 = fmaf(t, t, s00);
        t = a0.w - b0.w; s00 = fmaf(t, t, s00);
        t = a0.x - b1.x; s01 = fmaf(t, t, s01);
        t = a0.y - b1.y; s01 = fmaf(t, t, s01);
        t = a0.z - b1.z; s01 = fmaf(t, t, s01);
        t = a0.w - b1.w; s01 = fmaf(t, t, s01);
        t = a1.x - b0.x; s10 = fmaf(t, t, s10);
        t = a1.y - b0.y; s10 = fmaf(t, t, s10);
        t = a1.z - b0.z; s10 = fmaf(t, t, s10);
        t = a1.w - b0.w; s10 = fmaf(t, t, s10);
        t = a1.x - b1.x; s11 = fmaf(t, t, s11);
        t = a1.y - b1.y; s11 = fmaf(t, t, s11);
        t = a1.z - b1.z; s11 = fmaf(t, t, s11);
        t = a1.w - b1.w; s11 = fmaf(t, t, s11);
    }
    // safe_l2: identical rows give s == 0 exactly -> logit 0 (diagonal)
    float l00 = (s00 > 0.f) ? -0.5f * sqrtf(s00) : 0.f;
    float l01 = (s01 > 0.f) ? -0.5f * sqrtf(s01) : 0.f;
    float l10 = (s10 > 0.f) ? -0.5f * sqrtf(s10) : 0.f;
    float l11 = (s11 > 0.f) ? -0.5f * sqrtf(s11) : 0.f;

    *(float2*)(lg + (size_t)(row0 + r0) * N + col0 + c0) = make_float2(l00, l01);
    *(float2*)(lg + (size_t)(row0 + r1) * N + col0 + c0) = make_float2(l10, l11);
}

// ---------------- K23: fused per-row max/exp/denominator/loss (no atomics) ----------------
// Denominator loop: compare operand from cross-kernel ld2 (wave-uniform scalar
// reads -> s_load), exp values from in-kernel LDS broadcast (single LDS stream).
__global__ __launch_bounds__(256) void k23_row(const float* __restrict__ lg,
                                               const float* __restrict__ ld2,
                                               float* __restrict__ rowout) {
    const int i = blockIdx.x;
    const int c = threadIdx.x;

    __shared__ alignas(16) float sev[C];
    __shared__ float redm[4], reds[4], redl[4];
    __shared__ float lci;

    const float la = lg[(size_t)i * N + c];
    const float lb = lg[(size_t)i * N + c + 256];

    // row max over j != i (lg[i][i] == 0 excluded)
    float m = -1e30f;
    if (c != i) m = la;
    if (c + 256 != i) m = fmaxf(m, lb);
#pragma unroll
    for (int off = 32; off > 0; off >>= 1) m = fmaxf(m, __shfl_xor(m, off, 64));
    if ((c & 63) == 0) redm[c >> 6] = m;
    __syncthreads();
    m = fmaxf(fmaxf(redm[0], redm[1]), fmaxf(redm[2], redm[3]));

    // exp values; diagonal forced to 0 drops it from every denominator
    const float ea = (c == i) ? 0.f : __expf(la - m);
    const float eb = (c + 256 == i) ? 0.f : __expf(lb - m);
    sev[c] = ea + eb;

    // rowsum = sum_{k != i}(lg_k - m) = (sum_k lg_k) - 511*m   (lg_i == 0)
    float s = la + lb;
#pragma unroll
    for (int off = 32; off > 0; off >>= 1) s += __shfl_xor(s, off, 64);
    if ((c & 63) == 0) reds[c >> 6] = s;
    __syncthreads();                       // publishes sev + reds
    const float rowsum = (reds[0] + reds[1] + reds[2] + reds[3]) - 511.f * m;

    // denominator: ld2 via wave-uniform scalar loads (s_load path, written by K1),
    // sev via single-stream LDS float4 broadcasts.
    const float* __restrict__ rl = ld2 + (size_t)i * C;
    const float ldk = rl[c];
    const float4* e4 = (const float4*)sev;
    float d0 = 0.f, d1 = 0.f, d2 = 0.f, d3 = 0.f;
#pragma unroll 8
    for (int q = 0; q < C / 4; ++q) {
        const float a0 = rl[4 * q + 0], a1 = rl[4 * q + 1];
        const float a2 = rl[4 * q + 2], a3 = rl[4 * q + 3];
        const float4 ev = e4[q];
        d0 += (a0 >= ldk) ? ev.x : 0.f;
        d1 += (a1 >= ldk) ? ev.y : 0.f;
        d2 += (a2 >= ldk) ? ev.z : 0.f;
        d3 += (a3 >= ldk) ? ev.w : 0.f;
    }
    const float lden = __logf((d0 + d1) + (d2 + d3));

    if (c == (i & 255)) lci = lden;   // class(i): ld == 0 -> den == total ev sum
    float t = lden;
#pragma unroll
    for (int off = 32; off > 0; off >>= 1) t += __shfl_xor(t, off, 64);
    if ((c & 63) == 0) redl[c >> 6] = t;
    __syncthreads();
    if (c == 0) {
        const float tot = redl[0] + redl[1] + redl[2] + redl[3];
        rowout[i] = rowsum - (2.f * tot - lci);
    }
}

// ---------------- K4: final reduction ----------------
__global__ __launch_bounds__(256) void k4_reduce(const float* __restrict__ rowout,
                                                 float* __restrict__ out) {
    const int tid = threadIdx.x;
    double s = 0.0;
    for (int j = tid; j < N; j += 256) s += (double)rowout[j];
#pragma unroll
    for (int off = 32; off > 0; off >>= 1) s += __shfl_down(s, off, 64);
    __shared__ double sd[4];
    if ((tid & 63) == 0) sd[tid >> 6] = s;
    __syncthreads();
    if (tid == 0) {
        double t = sd[0] + sd[1] + sd[2] + sd[3];
        out[0] = (float)(-t / ((double)N * (double)(N - 1)));
    }
}

extern "C" void kernel_launch(void* const* d_in, const int* in_sizes, int n_in,
                              void* d_out, int out_size, void* d_ws, size_t ws_size,
                              hipStream_t stream) {
    const float* feat   = (const float*)d_in[0];   // [512,128] f32
    const float* labels = (const float*)d_in[1];   // [256,2]  f32
    float* out = (float*)d_out;

    float* lg     = (float*)d_ws;                  // N*N
    float* ld2    = lg + (size_t)N * N;            // N*C
    float* rowout = ld2 + (size_t)N * C;           // N

    k1_logits<<<256, 256, 0, stream>>>(feat, labels, lg, ld2);
    k23_row <<<N,   256, 0, stream>>>(lg, ld2, rowout);
    k4_reduce<<<1,  256, 0, stream>>>(rowout, out);
}